// Round 10
// baseline (185.846 us; speedup 1.0000x reference)
//
#include <hip/hip_runtime.h>
#include <hip/hip_fp16.h>

// dot_attention: out[b,n] = exp(diag*s - lse_n), s = (D/2)^-0.5 = 1/16.
// B=4, N=4096, D=512. Inputs fp32, output fp32.
// No fp32 MFMA on CDNA4 -> fp16 convert + mfma_f32_16x16x32_f16.
//
// R10: 64 q-rows/wave, single-wave (64-thr) blocks, NO barrier.
// LDS B-read total = waves*cols*K*2B: halving wave count (64 rows/wave,
// Af=256 regs, 1 wave/SIMD) drops LDS demand below the MFMA floor
// (20 vs 33 us/CU) -> MFMA-bound. Single-wave blocks make the dbuf
// handshake a pure per-wave s_waitcnt vmcnt(0) (explicit asm -> no
// R8-style compiler-inference race) with zero convoy: 4 independent
// waves/CU, LDS 4x32KB=128KB. Diag extracted to registers in-loop
// (wave-uniform compares), stored after the loop so no VMEM op rides
// the vmcnt queue mid-loop.

typedef _Float16 f16x8 __attribute__((ext_vector_type(8)));  // MFMA A/B frag (4 VGPR)
typedef float    f32x4 __attribute__((ext_vector_type(4)));  // MFMA C/D frag

#define NB 4
#define NN 4096
#define ND 512
#define SCALE 0.0625f
#define LOG2E 1.4426950408889634f
#define NROWS (NB * NN)            // 16384
#define FRAG_B 1024                // bytes per packed fragment
#define GRP_B  16384               // bytes per 16-row group (16 frags) = tile
#define CPITCH 520                 // convert LDS row pitch (halfwords) = 1040 B

__device__ __forceinline__ void gld16(const void* g, void* l) {
    __builtin_amdgcn_global_load_lds(
        (const __attribute__((address_space(1))) unsigned int*)g,
        (__attribute__((address_space(3))) unsigned int*)l, 16, 0, 0);
}

// Explicit DMA drain; never rely on compiler-inferred vmcnt for LDS-DMA
// consumption (R8 tripwire lesson).
__device__ __forceinline__ void vmfence() {
    asm volatile("s_waitcnt vmcnt(0)" ::: "memory");
}

__device__ __forceinline__ f16x8 cvt8(float4 a, float4 b) {
    f16x8 r;
    r[0] = (_Float16)a.x; r[1] = (_Float16)a.y; r[2] = (_Float16)a.z; r[3] = (_Float16)a.w;
    r[4] = (_Float16)b.x; r[5] = (_Float16)b.y; r[6] = (_Float16)b.z; r[7] = (_Float16)b.w;
    return r;
}

__device__ __forceinline__ f16x8 cvt8s(float4 a, float4 b, float s) {
    f16x8 r;
    r[0] = (_Float16)(a.x * s); r[1] = (_Float16)(a.y * s);
    r[2] = (_Float16)(a.z * s); r[3] = (_Float16)(a.w * s);
    r[4] = (_Float16)(b.x * s); r[5] = (_Float16)(b.y * s);
    r[6] = (_Float16)(b.z * s); r[7] = (_Float16)(b.w * s);
    return r;
}

__device__ __forceinline__ float sel4(const f32x4& a, int j) {
    return (j == 0) ? a[0] : (j == 1) ? a[1] : (j == 2) ? a[2] : a[3];
}

// ---- kernel 1: kv fp32 -> fp16, packed in B-frag order via LDS transpose.
// One 16-row group per block (1024 blocks). frag(g,kt) byte lane*16 =
// kv[g*16 + (lane&15)][kt*32 + (lane>>4)*8 ..+8) as fp16.
__launch_bounds__(256)
__global__ void convert_kernel(const float* __restrict__ kv,
                               _Float16* __restrict__ kvp) {
    __shared__ _Float16 s[16 * CPITCH];
    const int g    = blockIdx.x;
    const int tid  = threadIdx.x;
    const int wid  = tid >> 6;
    const int lane = tid & 63;
    const int l15  = lane & 15;
    const int quad = lane >> 4;

    #pragma unroll
    for (int i = 0; i < 4; ++i) {
        const int r = wid * 4 + i;
        const float* src = kv + ((size_t)g * 16 + r) * ND + lane * 8;
        float4 a = *(const float4*)src;
        float4 b = *(const float4*)(src + 4);
        *(f16x8*)(s + r * CPITCH + lane * 8) = cvt8(a, b);
    }
    __syncthreads();

    _Float16* dst = kvp + (size_t)g * 8192 + lane * 8;
    #pragma unroll
    for (int p = 0; p < 4; ++p) {
        const int kt = wid * 4 + p;
        f16x8 v = *(const f16x8*)(s + l15 * CPITCH + kt * 32 + quad * 8);
        *(f16x8*)(dst + kt * 512) = v;
    }
}

// ---- kernel 2: per-row sum of exp(score) over a 1024-column split + diag.
// grid (16: b*4+cs, 64: rowblock) = 1024 blocks of ONE 64-lane wave.
// 4 blocks/CU (4x32KB LDS), 1 wave/SIMD (512-reg budget: Af[4][16]=256).
// Per iter: one 16-row packed group, self-staged via 16 global_load_lds,
// drained with explicit vmcnt(0); 16 b128 LDS reads, 64 MFMA (4 indep
// acc chains saturate the MFMA pipe), 16 exp2.
__launch_bounds__(64, 1)
__global__ void lse_partial_kernel(const float* __restrict__ q,
                                   const _Float16* __restrict__ kvp,
                                   float* __restrict__ partial,
                                   float* __restrict__ diagsc) {
    __shared__ char sbuf[2][GRP_B];

    const int bc = blockIdx.x;          // b*4 + cs (fastest -> spread over XCDs)
    const int b  = bc >> 2;
    const int cs = bc & 3;
    const int rb = blockIdx.y;
    const int lane = threadIdx.x;       // 0..63
    const int l15  = lane & 15;
    const int quad = lane >> 4;

    const int row0 = rb * 64;           // wave's first q-row (in batch)
    const bool aligned = ((row0 >> 10) == cs);
    const int itd = aligned ? ((row0 & 1023) >> 4) : -100;  // m-tile 0 diag iter

    // ---- A fragments: q fp32 -> fp16 scaled by s*log2e (exp2 path).
    f16x8 Af[4][16];
    #pragma unroll
    for (int m = 0; m < 4; ++m) {
        const float* qrow = q + ((size_t)(b * NN + row0 + m * 16 + l15)) * ND + quad * 8;
        #pragma unroll
        for (int k = 0; k < 16; ++k) {
            float4 u0 = *(const float4*)(qrow + k * 32);
            float4 u1 = *(const float4*)(qrow + k * 32 + 4);
            Af[m][k] = cvt8s(u0, u1, SCALE * LOG2E);
        }
    }

    float lacc[4][4];
    #pragma unroll
    for (int m = 0; m < 4; ++m)
        #pragma unroll
        for (int j = 0; j < 4; ++j)
            lacc[m][j] = 0.f;

    float dsave[4] = {0.f, 0.f, 0.f, 0.f};

    // packed base for this (b,cs): 64 groups (= 64 tiles of 16 columns)
    const char* pb  = (const char*)kvp + ((size_t)(b * 256 + cs * 64)) * GRP_B;
    const char* ssb = pb + (size_t)lane * 16;

    // stage 16-frag tile `it_` into sbuf[buf_]: 16 frag-DMAs (whole wave)
    #define STAGE(it_, buf_)                                                  \
        do {                                                                  \
            const char* sp_ = ssb + (size_t)(it_) * GRP_B;                    \
            char* lb_ = sbuf[buf_];                                           \
            _Pragma("unroll")                                                 \
            for (int p_ = 0; p_ < 16; ++p_)                                   \
                gld16(sp_ + p_ * FRAG_B, lb_ + p_ * FRAG_B);                  \
        } while (0)

    STAGE(0, 0);
    int buf = 0;

    for (int it = 0; it < 64; ++it) {
        vmfence();                        // STAGE(it) landed (issued last iter)
        if (it + 1 < 64) STAGE(it + 1, buf ^ 1);

        const char* lb = sbuf[buf] + (size_t)lane * 16;
        f32x4 acc[4];
        #pragma unroll
        for (int m = 0; m < 4; ++m)
            acc[m] = (f32x4){0.f, 0.f, 0.f, 0.f};

        #pragma unroll
        for (int kt = 0; kt < 16; ++kt) {
            f16x8 b0 = *(const f16x8*)(lb + kt * FRAG_B);
            #pragma unroll
            for (int m = 0; m < 4; ++m)
                acc[m] = __builtin_amdgcn_mfma_f32_16x16x32_f16(Af[m][kt], b0, acc[m], 0, 0, 0);
        }

        // diag capture (wave-uniform compares; stores deferred past the loop
        // so nothing but STAGE DMAs ride the vmcnt queue).
        // C/D: row = quad*4+j, col = l15; diagonal lanes l15 == quad*4+j.
        if (it == itd)     dsave[0] = sel4(acc[0], l15 & 3);
        if (it == itd + 1) dsave[1] = sel4(acc[1], l15 & 3);
        if (it == itd + 2) dsave[2] = sel4(acc[2], l15 & 3);
        if (it == itd + 3) dsave[3] = sel4(acc[3], l15 & 3);

        // acc = score*log2e -> exp(score) = exp2(acc)
        #pragma unroll
        for (int m = 0; m < 4; ++m)
            #pragma unroll
            for (int j = 0; j < 4; ++j)
                lacc[m][j] += __builtin_amdgcn_exp2f(acc[m][j]);

        buf ^= 1;
    }

    // diag stores (only aligned waves; lanes where l15 == quad*4 + (l15&3))
    if (aligned && (l15 >> 2) == quad) {
        #pragma unroll
        for (int m = 0; m < 4; ++m)
            diagsc[b * NN + row0 + m * 16 + l15] = dsave[m];
    }

    // reduce over the 16 columns held across l15 lanes
    #pragma unroll
    for (int m = 0; m < 4; ++m)
        #pragma unroll
        for (int j = 0; j < 4; ++j) {
            float v = lacc[m][j];
            v += __shfl_xor(v, 1, 64);
            v += __shfl_xor(v, 2, 64);
            v += __shfl_xor(v, 4, 64);
            v += __shfl_xor(v, 8, 64);
            if (l15 == 0)
                partial[(size_t)cs * NROWS + b * NN + row0 + m * 16 + quad * 4 + j] = v;
        }
}

// ---- kernel 3: out = exp2(diag_scaled) / sum_cs partial
__launch_bounds__(256)
__global__ void finalize_kernel(const float* __restrict__ partial,
                                const float* __restrict__ diagsc,
                                float* __restrict__ out) {
    const int idx = blockIdx.x * 256 + threadIdx.x;
    float l = partial[idx] + partial[NROWS + idx] +
              partial[2 * NROWS + idx] + partial[3 * NROWS + idx];
    out[idx] = exp2f(diagsc[idx]) / l;
}

extern "C" void kernel_launch(void* const* d_in, const int* in_sizes, int n_in,
                              void* d_out, int out_size, void* d_ws, size_t ws_size,
                              hipStream_t stream) {
    const float* q  = (const float*)d_in[0];
    const float* kv = (const float*)d_in[1];
    float* out = (float*)d_out;

    // ws: kvp fp16 packed [16MB] | partial f32[4][16384] | diagsc f32[16384]
    _Float16* kvp   = (_Float16*)d_ws;
    float* partial  = (float*)((char*)d_ws + (size_t)NROWS * ND * 2);
    float* diagsc   = partial + 4 * NROWS;

    convert_kernel<<<1024, 256, 0, stream>>>(kv, kvp);
    lse_partial_kernel<<<dim3(16, 64), 64, 0, stream>>>(q, kvp, partial, diagsc);
    finalize_kernel<<<NROWS / 256, 256, 0, stream>>>(partial, diagsc, out);
}